// Round 4
// baseline (144.019 us; speedup 1.0000x reference)
//
#include <hip/hip_runtime.h>
#include <hip/hip_bf16.h>

typedef __bf16 bf16x8 __attribute__((ext_vector_type(8)));
typedef float  f32x4  __attribute__((ext_vector_type(4)));

#define BS 64       // rotation block size
#define RB 64       // number of rotation blocks
#define NELEM 2016  // strict upper-triangle element count
#define DD 4096     // feature dim
#define MROWS 16384 // 4 * 4096 rows
#define TILES 8     // 16-row tiles per wave

// ---------------------------------------------------------------------------
// Kernel A: build R[r] = I + 2Q + 2Q^2 + 2Q^3 + 2Q^4 (fp32), emit bf16 R in
// packed fragment order:
//   Rpk[((rblk*8 + kf*4 + n)*64 + lane)*8 + jj] =
//       bf16( R[32*kf + 8*(lane>>4) + jj][16*n + (lane&15)] )
// (B-frag of R == A-frag of R^T — same bits, used as MFMA operand A below.)
// One block per rblk, 512 threads: thread = (col j = t&63, 8 rows).
// ALL loops fully unrolled -> every array index compile-time -> registers
// (partial unroll demoted qcol[] to scratch in r2, +100us; rule #20).
// ---------------------------------------------------------------------------
__global__ __launch_bounds__(512) void rot_kernel(const float* __restrict__ w,
                                                  __bf16* __restrict__ Rpk) {
    const int blk = blockIdx.x;
    const int t   = threadIdx.x;
    __shared__ float Q [BS * BS];
    __shared__ float B0[BS * BS];
    __shared__ float B1[BS * BS];
    const float* wb = w + blk * NELEM;

    // Build skew-symmetric Q from strict upper triangle.
    for (int e = t; e < BS * BS; e += 512) {
        const int i = e >> 6, j = e & 63;
        float v = 0.f;
        if (i < j)      v =  wb[63 * i - (i * (i - 1)) / 2 + (j - i - 1)];
        else if (i > j) v = -wb[63 * j - (j * (j - 1)) / 2 + (i - j - 1)];
        Q[e] = v;
    }
    __syncthreads();

    const int j     = t & 63;        // column
    const int ibase = (t >> 6) * 8;  // 8 rows per thread

    // Q's column j in registers (reused by all 3 matmuls).
    float qcol[BS];
#pragma unroll
    for (int k = 0; k < BS; ++k) qcol[k] = Q[k * BS + j];

    float racc[8];
#pragma unroll
    for (int s = 0; s < 8; ++s) {
        const int i = ibase + s;
        racc[s] = (i == j ? 1.f : 0.f) + 2.f * Q[i * BS + j];
    }

    // Q^2, Q^3, Q^4 accumulated with weight 2. P reads are wave-uniform
    // broadcasts (conflict-free); qcol in registers.
    const float* P = Q;
    float*       T = B0;
    for (int pass = 0; pass < 3; ++pass) {
#pragma unroll
        for (int s = 0; s < 8; ++s) {
            const int i = ibase + s;
            float sum = 0.f;
#pragma unroll
            for (int k = 0; k < BS; ++k) sum += P[i * BS + k] * qcol[k];
            T[i * BS + j] = sum;
            racc[s] += 2.f * sum;
        }
        __syncthreads();
        P = T;
        T = (pass == 0) ? B1 : B0;
    }

    // Scatter-store into packed bf16 fragment layout.
#pragma unroll
    for (int s = 0; s < 8; ++s) {
        const int i  = ibase + s;        // k index of R[k][c]
        const int kf = i >> 5;           // K=32 fragment half
        const int g  = (i >> 3) & 3;     // lane group
        const int jj = i & 7;            // element within lane
        const int lane = 16 * g + (j & 15);
        const int n    = j >> 4;         // 16-col fragment
        Rpk[(size_t)((blk * 8 + kf * 4 + n) * 64 + lane) * 8 + jj] = (__bf16)racc[s];
    }
}

// ---------------------------------------------------------------------------
// Kernel B: y = x . R per 64-block, via mfma_f32_16x16x32_bf16 computing the
// TRANSPOSED product: acc = mfma(A = R^T frags, B = x frags) = y^T in C
// layout -> lane l&15 = y row, regs = 4 consecutive y cols. Stores are
// 4 x global_store_dwordx4 per 16x64 tile (64B contiguous per row per instr)
// instead of 16 scalar dwords. R entirely in registers; X global->reg in
// fragment order (each byte read once). No LDS, no barriers, normal stores
// (nt cost +25MB WRITE in r3).
// ---------------------------------------------------------------------------
__global__ __launch_bounds__(256) void apply_kernel(const float* __restrict__ x,
                                                    const __bf16* __restrict__ Rpk,
                                                    float* __restrict__ y) {
    const int tid  = threadIdx.x;
    const int l    = tid & 63;
    const int W    = blockIdx.x * 4 + (tid >> 6);
    const int rblk = W & 63;
    const int rg   = W >> 6;          // 0..127 row-groups of 128 rows
    const int g    = l >> 4;

    // Load the 8 R-fragments (coalesced 16B per lane).
    bf16x8 bfrag[2][4];
    const bf16x8* rp = reinterpret_cast<const bf16x8*>(Rpk) + (size_t)rblk * 8 * 64 + l;
#pragma unroll
    for (int kf = 0; kf < 2; ++kf)
#pragma unroll
        for (int n = 0; n < 4; ++n)
            bfrag[kf][n] = rp[(kf * 4 + n) * 64];

    const long rowbase = (long)rg * (TILES * 16);
    // Lane's x source: row = l&15 within tile, k-bytes at g*8 (+kf*32).
    const float* xlane = x + (rowbase + (l & 15)) * (long)DD + rblk * 64 + g * 8;

    const f32x4 zero = {0.f, 0.f, 0.f, 0.f};

    f32x4 v[4], vn[4];
#pragma unroll
    for (int q = 0; q < 4; ++q)
        v[q] = *reinterpret_cast<const f32x4*>(xlane + (q >> 1) * 32 + (q & 1) * 4);

#pragma unroll
    for (int t = 0; t < TILES; ++t) {
        // Prefetch next tile's X (independent of compute below).
        if (t + 1 < TILES) {
            const float* xp = xlane + (long)(t + 1) * 16 * DD;
#pragma unroll
            for (int q = 0; q < 4; ++q)
                vn[q] = *reinterpret_cast<const f32x4*>(xp + (q >> 1) * 32 + (q & 1) * 4);
        }

        // Convert to bf16 x-fragments (elem jj <-> k = 32kf + 8g + jj).
        bf16x8 a0, a1;
#pragma unroll
        for (int e = 0; e < 4; ++e) {
            a0[e]     = (__bf16)v[0][e];
            a0[e + 4] = (__bf16)v[1][e];
            a1[e]     = (__bf16)v[2][e];
            a1[e + 4] = (__bf16)v[3][e];
        }

        // Swapped operands: D = (R^T)(x^T) = y^T.
        f32x4 acc[4];
#pragma unroll
        for (int n = 0; n < 4; ++n)
            acc[n] = __builtin_amdgcn_mfma_f32_16x16x32_bf16(bfrag[0][n], a0, zero, 0, 0, 0);
#pragma unroll
        for (int n = 0; n < 4; ++n)
            acc[n] = __builtin_amdgcn_mfma_f32_16x16x32_bf16(bfrag[1][n], a1, acc[n], 0, 0, 0);

        // Lane holds y[row l&15][col 16n + 4g .. +3]: float4 stores.
        float* yl = y + (rowbase + t * 16 + (l & 15)) * (long)DD + rblk * 64 + 4 * g;
#pragma unroll
        for (int n = 0; n < 4; ++n) {
            f32x4 s4;
            s4[0] = acc[n][0]; s4[1] = acc[n][1];
            s4[2] = acc[n][2]; s4[3] = acc[n][3];
            *reinterpret_cast<f32x4*>(yl + n * 16) = s4;
        }

        if (t + 1 < TILES) {
#pragma unroll
            for (int q = 0; q < 4; ++q) v[q] = vn[q];
        }
    }
}

extern "C" void kernel_launch(void* const* d_in, const int* in_sizes, int n_in,
                              void* d_out, int out_size, void* d_ws, size_t ws_size,
                              hipStream_t stream) {
    (void)in_sizes; (void)n_in; (void)out_size; (void)ws_size;
    const float* x = (const float*)d_in[0];
    const float* w = (const float*)d_in[1];
    float* y = (float*)d_out;
    __bf16* Rpk = (__bf16*)d_ws;   // 64 rblk * 8 frags * 64 lanes * 8 bf16 = 512 KB

    rot_kernel<<<RB, 512, 0, stream>>>(w, Rpk);

    const int waves  = RB * (MROWS / (TILES * 16));  // 64 * 128 = 8192
    const int blocks = waves / 4;                    // 2048 blocks of 256 thr
    apply_kernel<<<blocks, 256, 0, stream>>>(x, Rpk, y);
}

// Round 5
// 141.762 us; speedup vs baseline: 1.0159x; 1.0159x over previous
//
#include <hip/hip_runtime.h>
#include <hip/hip_bf16.h>

typedef __bf16 bf16x8 __attribute__((ext_vector_type(8)));
typedef float  f32x4  __attribute__((ext_vector_type(4)));

#define BS 64       // rotation block size
#define RB 64       // number of rotation blocks
#define NELEM 2016  // strict upper-triangle element count
#define DD 4096     // feature dim
#define MROWS 16384 // 4 * 4096 rows
#define TILES 8     // 16-row tiles per wave

// ---------------------------------------------------------------------------
// Kernel A (r3-verified version): build R = I + 2Q + 2Q^2 + 2Q^3 + 2Q^4
// (fp32), emit bf16 R in packed fragment order:
//   Rpk[((rblk*8 + kf*4 + n)*64 + lane)*8 + jj] =
//       bf16( R[32*kf + 8*(lane>>4) + jj][16*n + (lane&15)] )
// One block per rblk, 256 threads: thread = (col j = t&63, 16 rows).
// ALL loops fully unrolled -> compile-time indices -> registers (rule #20).
// ---------------------------------------------------------------------------
__global__ __launch_bounds__(256) void rot_kernel(const float* __restrict__ w,
                                                  __bf16* __restrict__ Rpk) {
    const int blk = blockIdx.x;
    const int t   = threadIdx.x;
    __shared__ float Q [BS * BS];
    __shared__ float B0[BS * BS];
    __shared__ float B1[BS * BS];
    const float* wb = w + blk * NELEM;

    // Build skew-symmetric Q from strict upper triangle.
    for (int e = t; e < BS * BS; e += 256) {
        const int i = e >> 6, j = e & 63;
        float v = 0.f;
        if (i < j)      v =  wb[63 * i - (i * (i - 1)) / 2 + (j - i - 1)];
        else if (i > j) v = -wb[63 * j - (j * (j - 1)) / 2 + (i - j - 1)];
        Q[e] = v;
    }
    __syncthreads();

    const int j     = t & 63;        // column
    const int ibase = (t >> 6) << 4; // 16 rows per thread

    // Q's column j cached in registers (reused by all 3 matmuls).
    float qcol[BS];
#pragma unroll
    for (int k = 0; k < BS; ++k) qcol[k] = Q[k * BS + j];

    float racc[16];
#pragma unroll
    for (int s = 0; s < 16; ++s) {
        const int i = ibase + s;
        racc[s] = (i == j ? 1.f : 0.f) + 2.f * Q[i * BS + j];
    }

    // Q^2, Q^3, Q^4 accumulated with weight 2. P reads are wave-uniform
    // broadcasts (conflict-free); qcol in registers.
    const float* P = Q;
    float*       T = B0;
    for (int pass = 0; pass < 3; ++pass) {
#pragma unroll
        for (int s = 0; s < 16; ++s) {
            const int i = ibase + s;
            float sum = 0.f;
#pragma unroll
            for (int k = 0; k < BS; ++k) sum += P[i * BS + k] * qcol[k];
            T[i * BS + j] = sum;
            racc[s] += 2.f * sum;
        }
        __syncthreads();
        P = T;
        T = (pass == 0) ? B1 : B0;
    }

    // Scatter-store into packed bf16 fragment layout.
#pragma unroll
    for (int s = 0; s < 16; ++s) {
        const int i  = ibase + s;        // k index of R[k][c]
        const int kf = i >> 5;           // K=32 fragment half
        const int g  = (i >> 3) & 3;     // lane group
        const int jj = i & 7;            // element within lane
        const int lane = 16 * g + (j & 15);
        const int n    = j >> 4;         // 16-col fragment
        Rpk[(size_t)((blk * 8 + kf * 4 + n) * 64 + lane) * 8 + jj] = (__bf16)racc[s];
    }
}

// ---------------------------------------------------------------------------
// Kernel B: y = x . R per 64-block via mfma_f32_16x16x32_bf16 with SWAPPED
// operands (D = R^T x^T = y^T in C layout): lane l&15 = y row, regs = 4
// consecutive y cols -> stores are 4 x nontemporal global_store_dwordx4 per
// 16x64 tile (16 rows x 64B full sectors per instruction).
// NONTEMPORAL is load-bearing: y bypasses L2/L3 so ~half of x stays
// L3-resident across graph replays (r3: FETCH 133MB vs 256MB; removing nt in
// r4 cost +20us). R entirely in registers; X global->reg in fragment order;
// no LDS, no barriers.
// ---------------------------------------------------------------------------
__global__ __launch_bounds__(256) void apply_kernel(const float* __restrict__ x,
                                                    const __bf16* __restrict__ Rpk,
                                                    float* __restrict__ y) {
    const int tid  = threadIdx.x;
    const int l    = tid & 63;
    const int W    = blockIdx.x * 4 + (tid >> 6);
    const int rblk = W & 63;
    const int rg   = W >> 6;          // 0..127 row-groups of 128 rows
    const int g    = l >> 4;

    // Load the 8 R-fragments (coalesced 16B per lane).
    bf16x8 bfrag[2][4];
    const bf16x8* rp = reinterpret_cast<const bf16x8*>(Rpk) + (size_t)rblk * 8 * 64 + l;
#pragma unroll
    for (int kf = 0; kf < 2; ++kf)
#pragma unroll
        for (int n = 0; n < 4; ++n)
            bfrag[kf][n] = rp[(kf * 4 + n) * 64];

    const long rowbase = (long)rg * (TILES * 16);
    // Lane's x source: row = l&15 within tile, k-bytes at g*8 (+kf*32).
    const float* xlane = x + (rowbase + (l & 15)) * (long)DD + rblk * 64 + g * 8;

    const f32x4 zero = {0.f, 0.f, 0.f, 0.f};

    f32x4 v[4], vn[4];
#pragma unroll
    for (int q = 0; q < 4; ++q)
        v[q] = *reinterpret_cast<const f32x4*>(xlane + (q >> 1) * 32 + (q & 1) * 4);

#pragma unroll
    for (int t = 0; t < TILES; ++t) {
        // Prefetch next tile's X (independent of compute below).
        if (t + 1 < TILES) {
            const float* xp = xlane + (long)(t + 1) * 16 * DD;
#pragma unroll
            for (int q = 0; q < 4; ++q)
                vn[q] = *reinterpret_cast<const f32x4*>(xp + (q >> 1) * 32 + (q & 1) * 4);
        }

        // Convert to bf16 x-fragments (elem jj <-> k = 32kf + 8g + jj).
        bf16x8 a0, a1;
#pragma unroll
        for (int e = 0; e < 4; ++e) {
            a0[e]     = (__bf16)v[0][e];
            a0[e + 4] = (__bf16)v[1][e];
            a1[e]     = (__bf16)v[2][e];
            a1[e + 4] = (__bf16)v[3][e];
        }

        // Swapped operands: D = (R^T)(x^T) = y^T.
        f32x4 acc[4];
#pragma unroll
        for (int n = 0; n < 4; ++n)
            acc[n] = __builtin_amdgcn_mfma_f32_16x16x32_bf16(bfrag[0][n], a0, zero, 0, 0, 0);
#pragma unroll
        for (int n = 0; n < 4; ++n)
            acc[n] = __builtin_amdgcn_mfma_f32_16x16x32_bf16(bfrag[1][n], a1, acc[n], 0, 0, 0);

        // Lane holds y[row l&15][col 16n + 4g .. +3]: nontemporal float4.
        float* yl = y + (rowbase + t * 16 + (l & 15)) * (long)DD + rblk * 64 + 4 * g;
#pragma unroll
        for (int n = 0; n < 4; ++n) {
            f32x4 s4;
            s4[0] = acc[n][0]; s4[1] = acc[n][1];
            s4[2] = acc[n][2]; s4[3] = acc[n][3];
            __builtin_nontemporal_store(s4, reinterpret_cast<f32x4*>(yl + n * 16));
        }

        if (t + 1 < TILES) {
#pragma unroll
            for (int q = 0; q < 4; ++q) v[q] = vn[q];
        }
    }
}

extern "C" void kernel_launch(void* const* d_in, const int* in_sizes, int n_in,
                              void* d_out, int out_size, void* d_ws, size_t ws_size,
                              hipStream_t stream) {
    (void)in_sizes; (void)n_in; (void)out_size; (void)ws_size;
    const float* x = (const float*)d_in[0];
    const float* w = (const float*)d_in[1];
    float* y = (float*)d_out;
    __bf16* Rpk = (__bf16*)d_ws;   // 64 rblk * 8 frags * 64 lanes * 8 bf16 = 512 KB

    rot_kernel<<<RB, 256, 0, stream>>>(w, Rpk);

    const int waves  = RB * (MROWS / (TILES * 16));  // 64 * 128 = 8192
    const int blocks = waves / 4;                    // 2048 blocks of 256 thr
    apply_kernel<<<blocks, 256, 0, stream>>>(x, Rpk, y);
}

// Round 6
// 117.901 us; speedup vs baseline: 1.2215x; 1.2024x over previous
//
#include <hip/hip_runtime.h>
#include <hip/hip_bf16.h>

typedef __bf16 bf16x8 __attribute__((ext_vector_type(8)));
typedef float  f32x4  __attribute__((ext_vector_type(4)));

#define BS 64       // rotation block size
#define RB 64       // number of rotation blocks
#define NELEM 2016  // strict upper-triangle element count
#define DD 4096     // feature dim
#define MROWS 16384 // 4 * 4096 rows
#define TILES 8     // 16-row tiles per wave

// ---------------------------------------------------------------------------
// Kernel A (ROW-SPLIT): R = I + 2Q + 2Q^2 + 2Q^3 + 2Q^4, emitted as bf16 in
// packed fragment order:
//   Rpk[((rblk*8 + kf*4 + n)*64 + lane)*8 + jj] =
//       bf16( R[32*kf + 8*(lane>>4) + jj][16*n + (lane&15)] )
// Row-block recurrence: Q^{p+1}[i,:] = Q^p[i,:] . Q  -> a block owning 16
// rows needs only its own rows plus full Q. 4 blocks per rblk => 256 blocks
// (full chip) instead of 64; per-thread work drops 3072 -> 768 FMA.
// ALL loops fully unrolled -> compile-time indices -> registers (rule #20).
// ---------------------------------------------------------------------------
__global__ __launch_bounds__(256) void rot_kernel(const float* __restrict__ w,
                                                  __bf16* __restrict__ Rpk) {
    const int bid   = blockIdx.x;
    const int blk   = bid >> 2;          // rblk
    const int rbase = (bid & 3) * 16;    // this block's 16 rows of R
    const int t     = threadIdx.x;
    __shared__ float Q [BS * BS];
    __shared__ float T0[16 * BS];
    __shared__ float T1[16 * BS];
    const float* wb = w + blk * NELEM;

    // Build full skew-symmetric Q from strict upper triangle (redundant
    // across the 4 sibling blocks; w is tiny and L2-resident).
    for (int e = t; e < BS * BS; e += 256) {
        const int i = e >> 6, j = e & 63;
        float v = 0.f;
        if (i < j)      v =  wb[63 * i - (i * (i - 1)) / 2 + (j - i - 1)];
        else if (i > j) v = -wb[63 * j - (j * (j - 1)) / 2 + (i - j - 1)];
        Q[e] = v;
    }
    __syncthreads();

    const int j  = t & 63;         // column
    const int s4 = (t >> 6) * 4;   // first of this thread's 4 rows (relative)

    // Q's column j in registers (shared by all 3 passes).
    float qcol[BS];
#pragma unroll
    for (int k = 0; k < BS; ++k) qcol[k] = Q[k * BS + j];

    float racc[4];
#pragma unroll
    for (int s = 0; s < 4; ++s) {
        const int i = rbase + s4 + s;
        racc[s] = (i == j ? 1.f : 0.f) + 2.f * Q[i * BS + j];
    }

    // Pass 0: Q^2 rows (reads full Q rows — wave-uniform broadcasts).
#pragma unroll
    for (int s = 0; s < 4; ++s) {
        const int i = rbase + s4 + s;
        float sum = 0.f;
#pragma unroll
        for (int k = 0; k < BS; ++k) sum += Q[i * BS + k] * qcol[k];
        T0[(s4 + s) * BS + j] = sum;
        racc[s] += 2.f * sum;
    }
    __syncthreads();

    // Pass 1: Q^3 rows.
#pragma unroll
    for (int s = 0; s < 4; ++s) {
        const int r = s4 + s;
        float sum = 0.f;
#pragma unroll
        for (int k = 0; k < BS; ++k) sum += T0[r * BS + k] * qcol[k];
        T1[r * BS + j] = sum;
        racc[s] += 2.f * sum;
    }
    __syncthreads();

    // Pass 2: Q^4 rows (accumulate only).
#pragma unroll
    for (int s = 0; s < 4; ++s) {
        const int r = s4 + s;
        float sum = 0.f;
#pragma unroll
        for (int k = 0; k < BS; ++k) sum += T1[r * BS + k] * qcol[k];
        racc[s] += 2.f * sum;
    }

    // Scatter-store into packed bf16 fragment layout.
#pragma unroll
    for (int s = 0; s < 4; ++s) {
        const int i  = rbase + s4 + s;   // k index of R[k][c]
        const int kf = i >> 5;           // K=32 fragment half
        const int g  = (i >> 3) & 3;     // lane group
        const int jj = i & 7;            // element within lane
        const int lane = 16 * g + (j & 15);
        const int n    = j >> 4;         // 16-col fragment
        Rpk[(size_t)((blk * 8 + kf * 4 + n) * 64 + lane) * 8 + jj] = (__bf16)racc[s];
    }
}

// ---------------------------------------------------------------------------
// Kernel B: EXACT r3 apply (measured best: 124.4us total). y = x . R per
// 64-block via mfma_f32_16x16x32_bf16, NON-swapped operands, scalar
// nontemporal stores. R entirely in registers (8 B-frags); X global->reg in
// A-frag order (each byte read exactly once); no LDS, no barriers.
// r4/r5 "improvements" (operand swap + float4 stores) both measured slower
// in steady state — do not reintroduce without within-probe A/B.
// ---------------------------------------------------------------------------
__global__ __launch_bounds__(256) void apply_kernel(const float* __restrict__ x,
                                                    const __bf16* __restrict__ Rpk,
                                                    float* __restrict__ y) {
    const int tid  = threadIdx.x;
    const int l    = tid & 63;
    const int W    = blockIdx.x * 4 + (tid >> 6);
    const int rblk = W & 63;
    const int rg   = W >> 6;          // 0..127 row-groups of 128 rows
    const int g    = l >> 4;
    const int c    = l & 15;

    // Load the 8 B-fragments of R[rblk] (coalesced 16B per lane).
    bf16x8 bfrag[2][4];
    const bf16x8* rp = reinterpret_cast<const bf16x8*>(Rpk) + (size_t)rblk * 8 * 64 + l;
#pragma unroll
    for (int kf = 0; kf < 2; ++kf)
#pragma unroll
        for (int n = 0; n < 4; ++n)
            bfrag[kf][n] = rp[(kf * 4 + n) * 64];

    const long rowbase = (long)rg * (TILES * 16);
    // Lane's A-frag source: row = l&15 within tile, k-bytes at g*8 (+kf*32).
    const float* xlane = x + (rowbase + (l & 15)) * (long)DD + rblk * 64 + g * 8;

    const f32x4 zero = {0.f, 0.f, 0.f, 0.f};

    f32x4 v[4], vn[4];
#pragma unroll
    for (int q = 0; q < 4; ++q)
        v[q] = *reinterpret_cast<const f32x4*>(xlane + (q >> 1) * 32 + (q & 1) * 4);

#pragma unroll
    for (int t = 0; t < TILES; ++t) {
        // Prefetch next tile's X (independent of compute below).
        if (t + 1 < TILES) {
            const float* xp = xlane + (long)(t + 1) * 16 * DD;
#pragma unroll
            for (int q = 0; q < 4; ++q)
                vn[q] = *reinterpret_cast<const f32x4*>(xp + (q >> 1) * 32 + (q & 1) * 4);
        }

        // Convert to bf16 A-fragments (elements jj <-> k = 32kf + 8g + jj).
        bf16x8 a0, a1;
#pragma unroll
        for (int e = 0; e < 4; ++e) {
            a0[e]     = (__bf16)v[0][e];
            a0[e + 4] = (__bf16)v[1][e];
            a1[e]     = (__bf16)v[2][e];
            a1[e + 4] = (__bf16)v[3][e];
        }

        f32x4 acc[4];
#pragma unroll
        for (int n = 0; n < 4; ++n)
            acc[n] = __builtin_amdgcn_mfma_f32_16x16x32_bf16(a0, bfrag[0][n], zero, 0, 0, 0);
#pragma unroll
        for (int n = 0; n < 4; ++n)
            acc[n] = __builtin_amdgcn_mfma_f32_16x16x32_bf16(a1, bfrag[1][n], acc[n], 0, 0, 0);

        // Store: lane holds rows 4g+i, col c+16n of this 16x64 tile.
        // Nontemporal: y is write-once; keep L2/L3 capacity for x.
        float* yl = y + (rowbase + t * 16 + 4 * g) * (long)DD + rblk * 64 + c;
#pragma unroll
        for (int n = 0; n < 4; ++n)
#pragma unroll
            for (int i = 0; i < 4; ++i)
                __builtin_nontemporal_store(acc[n][i], yl + (long)i * DD + n * 16);

        if (t + 1 < TILES) {
#pragma unroll
            for (int q = 0; q < 4; ++q) v[q] = vn[q];
        }
    }
}

extern "C" void kernel_launch(void* const* d_in, const int* in_sizes, int n_in,
                              void* d_out, int out_size, void* d_ws, size_t ws_size,
                              hipStream_t stream) {
    (void)in_sizes; (void)n_in; (void)out_size; (void)ws_size;
    const float* x = (const float*)d_in[0];
    const float* w = (const float*)d_in[1];
    float* y = (float*)d_out;
    __bf16* Rpk = (__bf16*)d_ws;   // 64 rblk * 8 frags * 64 lanes * 8 bf16 = 512 KB

    rot_kernel<<<RB * 4, 256, 0, stream>>>(w, Rpk);

    const int waves  = RB * (MROWS / (TILES * 16));  // 64 * 128 = 8192
    const int blocks = waves / 4;                    // 2048 blocks of 256 thr
    apply_kernel<<<blocks, 256, 0, stream>>>(x, Rpk, y);
}